// Round 7
// baseline (291.294 us; speedup 1.0000x reference)
//
#include <hip/hip_runtime.h>
#include <hip/hip_bf16.h>
#include <math.h>

#define B_  2
#define S_  2048
#define D_  1024
#define H_  16
#define HD_ 64
#define M_  (B_*S_)      // 4096 (b,s) rows
#define BH_ (B_*H_)      // 32
#define QKSCALE 0.18033688011112042f   // 0.125 * log2(e), folded into Q

typedef __attribute__((ext_vector_type(8)))  short  bf16x8;
typedef __attribute__((ext_vector_type(4)))  float  f32x4;

#define MFMA16(a,b,c) __builtin_amdgcn_mfma_f32_16x16x32_bf16(a,b,c,0,0,0)

// ---- device scratch (~97 MB) ----
__device__ float          g_vp[(size_t)M_ * D_];     // roped V projection fp32; later PV partial z=0
__device__ float          g_p1[(size_t)M_ * D_];     // PV partial z=1
__device__ float          g_p2[(size_t)M_ * D_];     // PV partial z=2
__device__ float          g_p3[(size_t)M_ * D_];     // PV partial z=3
__device__ unsigned short g_q16[(size_t)M_ * D_];    // roped+scaled Q  [bh][s][64] (flat view)
__device__ unsigned short g_k16[(size_t)M_ * D_];    // roped K
__device__ unsigned short g_v16t[(size_t)M_ * D_];   // roped,*1/Z, V^T [bh][64 d][2048 s]
__device__ unsigned short g_x16[(size_t)M_ * D_];    // attn out, (b,s,D) layout
__device__ float          g_rz[BH_ * S_];            // 1/Z per (bh, key s)
__device__ float          g_tab[S_ * 64];            // cos/sin interleaved

static __device__ __forceinline__ unsigned short f2b(float x){
  union { float f; unsigned u; } v; v.f = x;
  unsigned r = v.u + 0x7FFFu + ((v.u >> 16) & 1u);   // RNE
  return (unsigned short)(r >> 16);
}
static __device__ __forceinline__ unsigned cvtpk(float lo, float hi){
  unsigned r;
  asm("v_cvt_pk_bf16_f32 %0, %1, %2" : "=v"(r) : "v"(lo), "v"(hi));
  return r;
}

// ------------------------------------------------ cos/sin table
__global__ void k_table(const int* __restrict__ pos){
  int i = blockIdx.x * 256 + threadIdx.x;
  if (i >= S_ * 32) return;
  int s = i >> 5, f = i & 31;
  float ang = (float)pos[s] * powf(10000.0f, -(float)f * (1.0f/32.0f));
  g_tab[2*i]   = cosf(ang);
  g_tab[2*i+1] = sinf(ang);
}

// ------------------------------------------------ Q: RoPE + scale -> bf16 (flat head view)
__global__ void k_ropeq(const float* __restrict__ in){
  const int i = blockIdx.x * 256 + threadIdx.x;   // pair index
  const int grp = i >> 5, d = i & 31;
  const int s = grp & (S_ - 1);                   // s' in (B,H,S,hd) view
  const size_t base = (size_t)grp * 64;
  const float x1 = in[base + d];
  const float x2 = in[base + d + 32];
  const float c  = g_tab[(s*32 + d)*2];
  const float sn = g_tab[(s*32 + d)*2 + 1];
  g_q16[base + d]      = f2b((x1*c - x2*sn) * QKSCALE);
  g_q16[base + d + 32] = f2b((x2*c + x1*sn) * QKSCALE);
}

// ------------------------------------------------ fused K/V projection GEMM (fp32 in, cvt-on-stage)
// z=0: C = rope(key @ Wk^T + bk) -> g_k16 (bf16)
// z=1: C = rope(value @ Wv^T + bv) -> g_vp (fp32)
// RoPE position: projection elem (s, dd) sits at head-view s' = (s&127)*16 + (dd>>6)
__global__ __launch_bounds__(256) void k_proj(const float* __restrict__ key,
                                              const float* __restrict__ value,
                                              const float* __restrict__ Wk,
                                              const float* __restrict__ bk,
                                              const float* __restrict__ Wv,
                                              const float* __restrict__ bv){
  __shared__ __align__(16) unsigned short As[128*64];
  __shared__ __align__(16) unsigned short Bs[128*64];
  const int z = blockIdx.z;
  const float* A    = z ? value : key;
  const float* W    = z ? Wv : Wk;
  const float* bias = z ? bv : bk;
  const int t = threadIdx.x, l = t & 63, wid = t >> 6;
  const int wm = wid >> 1, wn = wid & 1;
  const int rowB = blockIdx.y * 128, colB = blockIdx.x * 128;
  f32x4 acc[4][4];
  #pragma unroll
  for (int i = 0; i < 4; ++i)
    #pragma unroll
    for (int j = 0; j < 4; ++j)
      #pragma unroll
      for (int r = 0; r < 4; ++r) acc[i][j][r] = 0.f;

  const int srow = t >> 3, se = (t & 7) * 8;   // element offset within 64
  float4 a0[4], a1[4], b0[4], b1[4];
#define GLD(K0) \
  for (int u = 0; u < 4; ++u){ \
    const int row = srow + u*32; \
    const float* ap = A + (size_t)(rowB+row)*D_ + (K0) + se; \
    const float* wp = W + (size_t)(colB+row)*D_ + (K0) + se; \
    a0[u] = *(const float4*)ap; a1[u] = *(const float4*)(ap+4); \
    b0[u] = *(const float4*)wp; b1[u] = *(const float4*)(wp+4); \
  }
  GLD(0);
  for (int k0 = 0; k0 < D_; k0 += 64){
    __syncthreads();
    #pragma unroll
    for (int u = 0; u < 4; ++u){
      const int row = srow + u*32;
      const int off = row*128 + ((se*2) ^ ((row & 7) << 4));
      uint4 pa, pb;
      pa.x = cvtpk(a0[u].x, a0[u].y); pa.y = cvtpk(a0[u].z, a0[u].w);
      pa.z = cvtpk(a1[u].x, a1[u].y); pa.w = cvtpk(a1[u].z, a1[u].w);
      pb.x = cvtpk(b0[u].x, b0[u].y); pb.y = cvtpk(b0[u].z, b0[u].w);
      pb.z = cvtpk(b1[u].x, b1[u].y); pb.w = cvtpk(b1[u].z, b1[u].w);
      *(uint4*)((char*)As + off) = pa;
      *(uint4*)((char*)Bs + off) = pb;
    }
    __syncthreads();
    if (k0 + 64 < D_){ GLD(k0 + 64); }
    #pragma unroll
    for (int kk = 0; kk < 2; ++kk){
      const int cb = kk*64 + (l >> 4) * 16;
      bf16x8 af[4], bfr[4];
      #pragma unroll
      for (int mi = 0; mi < 4; ++mi){
        const int row = wm*64 + mi*16 + (l & 15);
        af[mi] = *(const bf16x8*)((const char*)As + row*128 + (cb ^ ((row & 7) << 4)));
      }
      #pragma unroll
      for (int ni = 0; ni < 4; ++ni){
        const int row = wn*64 + ni*16 + (l & 15);
        bfr[ni] = *(const bf16x8*)((const char*)Bs + row*128 + (cb ^ ((row & 7) << 4)));
      }
      #pragma unroll
      for (int mi = 0; mi < 4; ++mi)
        #pragma unroll
        for (int ni = 0; ni < 4; ++ni)
          acc[mi][ni] = MFMA16(af[mi], bfr[ni], acc[mi][ni]);
    }
  }
#undef GLD
  // epilogue: bias + RoPE (pairs are ni and ni+2: cols 32 apart within a head)
  const int ql15 = l & 15, r4 = (l >> 4) * 4;
  const int hcol = (colB >> 6) + wn;              // dd>>6, wave-uniform
  #pragma unroll
  for (int mi = 0; mi < 4; ++mi){
    #pragma unroll
    for (int r = 0; r < 4; ++r){
      const int row = rowB + wm*64 + mi*16 + r4 + r;
      const int pos = ((row & 127) << 4) + hcol;  // head-view position s'
      #pragma unroll
      for (int ni = 0; ni < 2; ++ni){
        const int col = colB + wn*64 + ni*16 + ql15;   // (col & 63) < 32
        const int f = ni*16 + ql15;
        const float c  = g_tab[(pos*32 + f)*2];
        const float sn = g_tab[(pos*32 + f)*2 + 1];
        const float x1 = acc[mi][ni][r]   + bias[col];
        const float x2 = acc[mi][ni+2][r] + bias[col+32];
        const float o1 = x1*c - x2*sn;
        const float o2 = x2*c + x1*sn;
        if (z){
          g_vp[(size_t)row*D_ + col]      = o1;
          g_vp[(size_t)row*D_ + col + 32] = o2;
        } else {
          g_k16[(size_t)row*D_ + col]      = f2b(o1);
          g_k16[(size_t)row*D_ + col + 32] = f2b(o2);
        }
      }
    }
  }
}

// ------------------------------------------------ output GEMM: out = x16 @ Wo^T + bo (Wo fp32, cvt-on-stage)
__global__ __launch_bounds__(256) void k_gemm_out(const unsigned short* __restrict__ A,
                                                  const float* __restrict__ W,
                                                  const float* __restrict__ bias,
                                                  float* __restrict__ C){
  __shared__ __align__(16) unsigned short As[128*64];
  __shared__ __align__(16) unsigned short Bs[128*64];
  const int t = threadIdx.x, l = t & 63, wid = t >> 6;
  const int wm = wid >> 1, wn = wid & 1;
  const int rowB = blockIdx.y * 128, colB = blockIdx.x * 128;
  f32x4 acc[4][4];
  #pragma unroll
  for (int i = 0; i < 4; ++i)
    #pragma unroll
    for (int j = 0; j < 4; ++j)
      #pragma unroll
      for (int r = 0; r < 4; ++r) acc[i][j][r] = 0.f;

  const int srow = t >> 3, se = (t & 7) * 8, scb = (t & 7) * 16;
  float4 ar[4], b0[4], b1[4];
#define GLD(K0) \
  for (int u = 0; u < 4; ++u){ \
    const int row = srow + u*32; \
    ar[u] = *(const float4*)((const char*)(A + (size_t)(rowB+row)*D_ + (K0)) + scb); \
    const float* wp = W + (size_t)(colB+row)*D_ + (K0) + se; \
    b0[u] = *(const float4*)wp; b1[u] = *(const float4*)(wp+4); \
  }
  GLD(0);
  for (int k0 = 0; k0 < D_; k0 += 64){
    __syncthreads();
    #pragma unroll
    for (int u = 0; u < 4; ++u){
      const int row = srow + u*32;
      const int off = row*128 + (scb ^ ((row & 7) << 4));
      uint4 pb;
      pb.x = cvtpk(b0[u].x, b0[u].y); pb.y = cvtpk(b0[u].z, b0[u].w);
      pb.z = cvtpk(b1[u].x, b1[u].y); pb.w = cvtpk(b1[u].z, b1[u].w);
      *(float4*)((char*)As + off) = ar[u];
      *(uint4*)((char*)Bs + off) = pb;
    }
    __syncthreads();
    if (k0 + 64 < D_){ GLD(k0 + 64); }
    #pragma unroll
    for (int kk = 0; kk < 2; ++kk){
      const int cb = kk*64 + (l >> 4) * 16;
      bf16x8 af[4], bfr[4];
      #pragma unroll
      for (int mi = 0; mi < 4; ++mi){
        const int row = wm*64 + mi*16 + (l & 15);
        af[mi] = *(const bf16x8*)((const char*)As + row*128 + (cb ^ ((row & 7) << 4)));
      }
      #pragma unroll
      for (int ni = 0; ni < 4; ++ni){
        const int row = wn*64 + ni*16 + (l & 15);
        bfr[ni] = *(const bf16x8*)((const char*)Bs + row*128 + (cb ^ ((row & 7) << 4)));
      }
      #pragma unroll
      for (int mi = 0; mi < 4; ++mi)
        #pragma unroll
        for (int ni = 0; ni < 4; ++ni)
          acc[mi][ni] = MFMA16(af[mi], bfr[ni], acc[mi][ni]);
    }
  }
#undef GLD
  #pragma unroll
  for (int mi = 0; mi < 4; ++mi){
    #pragma unroll
    for (int ni = 0; ni < 4; ++ni){
      const int col = colB + wn*64 + ni*16 + (l & 15);
      const float bb = bias[col];
      #pragma unroll
      for (int r = 0; r < 4; ++r){
        const int row = rowB + wm*64 + mi*16 + (l >> 4)*4 + r;
        C[(size_t)row * D_ + col] = acc[mi][ni][r] + bb;
      }
    }
  }
}

// ------------------------------------------------ pass 1: Z_k = sum_q exp(s_qk), diag s=0
// block = 4 waves on the SAME 64 keys; each wave sums a 512-q quarter; LDS combine.
__global__ __launch_bounds__(256) void k_pass1(){
  __shared__ float zs[4][4][16];
  const int t = threadIdx.x, l = t & 63, wid = t >> 6;
  const int bh = blockIdx.y;
  const int kwb = blockIdx.x * 64;
  const unsigned short* Qp = g_q16 + (size_t)bh * S_ * HD_;
  const unsigned short* Kp = g_k16 + (size_t)bh * S_ * HD_;
  bf16x8 bk_[4][2];
  #pragma unroll
  for (int kb = 0; kb < 4; ++kb){
    const unsigned short* kr = Kp + (size_t)(kwb + kb*16 + (l & 15)) * HD_ + (l >> 4) * 8;
    bk_[kb][0] = *(const bf16x8*)(kr);
    bk_[kb][1] = *(const bf16x8*)(kr + 32);
  }
  float zz[4] = {0.f, 0.f, 0.f, 0.f};
  const int qBeg = wid * (S_/4);
  for (int qi = 0; qi < S_/4; qi += 16){
    const int q0 = qBeg + qi;
    const unsigned short* qr = Qp + (size_t)(q0 + (l & 15)) * HD_ + (l >> 4) * 8;
    bf16x8 a0 = *(const bf16x8*)(qr);
    bf16x8 a1 = *(const bf16x8*)(qr + 32);
    #pragma unroll
    for (int kb = 0; kb < 4; ++kb){
      f32x4 c = {0.f, 0.f, 0.f, 0.f};
      c = MFMA16(a0, bk_[kb][0], c);
      c = MFMA16(a1, bk_[kb][1], c);
      if (q0 == kwb + kb*16){          // wave-uniform: diagonal tile
        const int kg = kwb + kb*16 + (l & 15);
        #pragma unroll
        for (int r = 0; r < 4; ++r)
          zz[kb] += (q0 + (l >> 4)*4 + r == kg) ? 1.0f : exp2f(c[r]);
      } else {
        zz[kb] += exp2f(c[0]) + exp2f(c[1]) + exp2f(c[2]) + exp2f(c[3]);
      }
    }
  }
  #pragma unroll
  for (int kb = 0; kb < 4; ++kb){
    float z = zz[kb];
    z += __shfl_xor(z, 16); z += __shfl_xor(z, 32);
    if (l < 16) zs[wid][kb][l] = z;
  }
  __syncthreads();
  if (t < 64){
    const int kb = t >> 4, ki = t & 15;
    const float Z = zs[0][kb][ki] + zs[1][kb][ki] + zs[2][kb][ki] + zs[3][kb][ki];
    g_rz[bh*S_ + kwb + kb*16 + ki] = 1.0f / Z;
  }
}

// ------------------------------------------------ V fixup: *1/Z + transpose -> bf16 [bh][d][s] (already roped)
__global__ __launch_bounds__(256) void k_vfix(){
  __shared__ __align__(16) float tile[64][68];
  const int t = threadIdx.x;
  const int bh = blockIdx.y;
  const int s0 = blockIdx.x * 64;
  #pragma unroll
  for (int u = 0; u < 4; ++u){
    const int i = t + u*256;
    const int row = i >> 4, c4 = (i & 15) * 4;
    *(float4*)&tile[row][c4] = *(const float4*)(g_vp + (size_t)(bh*S_ + s0 + row) * HD_ + c4);
  }
  __syncthreads();
  const int d = t >> 2;
  const int sc = (t & 3) * 16;
  float rzv[16];
  #pragma unroll
  for (int u = 0; u < 4; ++u)
    *(float4*)&rzv[u*4] = *(const float4*)(g_rz + bh*S_ + s0 + sc + u*4);
  unsigned w[8];
  #pragma unroll
  for (int j2 = 0; j2 < 8; ++j2)
    w[j2] = cvtpk(tile[sc + 2*j2][d] * rzv[2*j2], tile[sc + 2*j2 + 1][d] * rzv[2*j2 + 1]);
  unsigned short* dst = g_v16t + (size_t)(bh*HD_ + d) * S_ + s0 + sc;
  *(uint4*)(dst)     = *(uint4*)&w[0];
  *(uint4*)(dst + 8) = *(uint4*)&w[4];
}

// ------------------------------------------------ pass 2: out[q,:] = sum_k exp(s_qk) * V'[k,:]
// BARRIER-FREE: K and V' fragments read directly from global (L2-resident per head).
// LDS holds only the per-wave P buffer (double-buffered). blockIdx.z = key quarter.
__global__ __launch_bounds__(256, 4) void k_pass2(){
  __shared__ __align__(16) unsigned short Ps[2][4][32*64];   // [buf][wave][q][k] swizzled
  const int t = threadIdx.x, l = t & 63, wid = t >> 6;
  const int bh = blockIdx.y;
  const int z = blockIdx.z;
  const int b = bh >> 4, hh = bh & 15;
  const int q0 = blockIdx.x * 128;
  const unsigned short* Qp = g_q16  + (size_t)bh * S_ * HD_;
  const unsigned short* Kp = g_k16  + (size_t)bh * S_ * HD_;
  const unsigned short* Vp = g_v16t + (size_t)bh * HD_ * S_;
  float* Op = (z == 0) ? g_vp : (z == 1) ? g_p1 : (z == 2) ? g_p2 : g_p3;
  const int ql = l & 15, kq = l >> 4;
  const int qb = q0 + wid*32;

  bf16x8 qf[2][2];
  #pragma unroll
  for (int h = 0; h < 2; ++h){
    const unsigned short* qr = Qp + (size_t)(qb + h*16 + ql) * HD_ + kq * 8;
    qf[h][0] = *(const bf16x8*)(qr);
    qf[h][1] = *(const bf16x8*)(qr + 32);
  }
  f32x4 co[4][2];
  #pragma unroll
  for (int nd = 0; nd < 4; ++nd)
    #pragma unroll
    for (int h = 0; h < 2; ++h)
      #pragma unroll
      for (int r = 0; r < 4; ++r) co[nd][h][r] = 0.f;

  const int kg0 = z * (S_/4);
  #pragma unroll 2
  for (int kt = 0; kt < 8; ++kt){
    const int k0 = kg0 + kt * 64;
    char* Pw = (char*)&Ps[kt & 1][wid][0];
    // ---- swapped QK^T: D[key16][q16]; A = K rows from GLOBAL, B = Q (regs)
    f32x4 cst[4][2];
    #pragma unroll
    for (int kb = 0; kb < 4; ++kb)
      #pragma unroll
      for (int h = 0; h < 2; ++h)
        #pragma unroll
        for (int r = 0; r < 4; ++r) cst[kb][h][r] = 0.f;
    #pragma unroll
    for (int kb = 0; kb < 4; ++kb){
      const unsigned short* kr = Kp + (size_t)(k0 + kb*16 + ql) * HD_ + kq * 8;
      bf16x8 kf0 = *(const bf16x8*)(kr);        // k-slice [0,32)
      bf16x8 kf1 = *(const bf16x8*)(kr + 32);   // k-slice [32,64)
      cst[kb][0] = MFMA16(kf0, qf[0][0], cst[kb][0]);
      cst[kb][0] = MFMA16(kf1, qf[0][1], cst[kb][0]);
      cst[kb][1] = MFMA16(kf0, qf[1][0], cst[kb][1]);
      cst[kb][1] = MFMA16(kf1, qf[1][1], cst[kb][1]);
    }
    // ---- exp -> bf16 pairs -> per-wave LDS (diag only on overlap tiles; wave-uniform)
    const bool diag = (k0 < qb + 32) && (qb < k0 + 64);
    #pragma unroll
    for (int h = 0; h < 2; ++h){
      const int qg = qb + h*16 + ql;
      #pragma unroll
      for (int kb = 0; kb < 4; ++kb){
        float e[4];
        if (diag){
          #pragma unroll
          for (int r = 0; r < 4; ++r){
            const int key = k0 + kb*16 + kq*4 + r;
            e[r] = (qg == key) ? 1.0f : exp2f(cst[kb][h][r]);
          }
        } else {
          #pragma unroll
          for (int r = 0; r < 4; ++r) e[r] = exp2f(cst[kb][h][r]);
        }
        uint2 w;
        w.x = cvtpk(e[0], e[1]);
        w.y = cvtpk(e[2], e[3]);
        *(uint2*)(Pw + (h*16 + ql)*128 + ((kb*32 + kq*8) ^ ((ql & 7) << 4))) = w;
      }
    }
    // ---- PV: D[q16][d16]; A = P rows (LDS), B = V' rows from GLOBAL
    #pragma unroll
    for (int sl = 0; sl < 2; ++sl){
      bf16x8 pf0 = *(const bf16x8*)(Pw + (0*16 + ql)*128 + ((sl*64 + kq*16) ^ ((ql & 7) << 4)));
      bf16x8 pf1 = *(const bf16x8*)(Pw + (1*16 + ql)*128 + ((sl*64 + kq*16) ^ ((ql & 7) << 4)));
      #pragma unroll
      for (int nd = 0; nd < 4; ++nd){
        const unsigned short* vr = Vp + (size_t)(nd*16 + ql) * S_ + k0 + sl*32 + kq*8;
        bf16x8 vf = *(const bf16x8*)(vr);
        co[nd][0] = MFMA16(pf0, vf, co[nd][0]);
        co[nd][1] = MFMA16(pf1, vf, co[nd][1]);
      }
    }
  }
  // epilogue: fp32 partial, (b,s,D) layout
  #pragma unroll
  for (int h = 0; h < 2; ++h){
    #pragma unroll
    for (int nd = 0; nd < 4; ++nd){
      const int d = nd*16 + ql;
      #pragma unroll
      for (int r = 0; r < 4; ++r){
        const int q = qb + h*16 + kq*4 + r;
        Op[(size_t)(b*S_ + q) * D_ + hh*HD_ + d] = co[nd][h][r];
      }
    }
  }
}

// ------------------------------------------------ combine 4 PV partials -> bf16
__global__ void k_reduce(){
  const int i = blockIdx.x * 256 + threadIdx.x;
  const size_t off = (size_t)i * 8;
  float4 a0 = *(const float4*)(g_vp + off), a1 = *(const float4*)(g_vp + off + 4);
  float4 b0 = *(const float4*)(g_p1 + off), b1 = *(const float4*)(g_p1 + off + 4);
  float4 c0 = *(const float4*)(g_p2 + off), c1 = *(const float4*)(g_p2 + off + 4);
  float4 d0 = *(const float4*)(g_p3 + off), d1 = *(const float4*)(g_p3 + off + 4);
  uint4 w;
  w.x = cvtpk(a0.x + b0.x + c0.x + d0.x, a0.y + b0.y + c0.y + d0.y);
  w.y = cvtpk(a0.z + b0.z + c0.z + d0.z, a0.w + b0.w + c0.w + d0.w);
  w.z = cvtpk(a1.x + b1.x + c1.x + d1.x, a1.y + b1.y + c1.y + d1.y);
  w.w = cvtpk(a1.z + b1.z + c1.z + d1.z, a1.w + b1.w + c1.w + d1.w);
  *(uint4*)(g_x16 + off) = w;
}

extern "C" void kernel_launch(void* const* d_in, const int* in_sizes, int n_in,
                              void* d_out, int out_size, void* d_ws, size_t ws_size,
                              hipStream_t stream) {
  const float* query = (const float*)d_in[0];
  const float* key   = (const float*)d_in[1];
  const float* value = (const float*)d_in[2];
  const int*   pos   = (const int*)  d_in[3];
  const float* Wk    = (const float*)d_in[4];
  const float* bk    = (const float*)d_in[5];
  const float* Wv    = (const float*)d_in[6];
  const float* bv    = (const float*)d_in[7];
  const float* Wo    = (const float*)d_in[8];
  const float* bo    = (const float*)d_in[9];
  float* out = (float*)d_out;

  unsigned short* px16; hipGetSymbolAddress((void**)&px16, HIP_SYMBOL(g_x16));

  k_table<<<256, 256, 0, stream>>>(pos);

  dim3 gP(D_/128, M_/128, 2);   // (8, 32, 2)
  k_proj<<<gP, 256, 0, stream>>>(key, value, Wk, bk, Wv, bv);  // -> g_k16 (roped bf16), g_vp (roped fp32)

  k_ropeq<<<8192, 256, 0, stream>>>(query);                    // -> g_q16 (roped, scaled)

  k_pass1<<<dim3(S_/64, BH_), 256, 0, stream>>>();             // -> g_rz   (1024 blocks)
  k_vfix <<<dim3(32, BH_), 256, 0, stream>>>();                // g_vp -> g_v16t (*1/Z, transposed)
  k_pass2<<<dim3(16, BH_, 4), 256, 0, stream>>>();             // -> 4 fp32 partials (2048 blocks)
  k_reduce<<<(M_*D_/8)/256, 256, 0, stream>>>();               // -> g_x16

  dim3 gO(D_/128, M_/128);      // (8, 32)
  k_gemm_out<<<gO, 256, 0, stream>>>(px16, Wo, bo, out);       // output proj
}

// Round 8
// 260.921 us; speedup vs baseline: 1.1164x; 1.1164x over previous
//
#include <hip/hip_runtime.h>
#include <hip/hip_bf16.h>
#include <math.h>

#define B_  2
#define S_  2048
#define D_  1024
#define H_  16
#define HD_ 64
#define M_  (B_*S_)      // 4096 (b,s) rows
#define BH_ (B_*H_)      // 32
#define QKSCALE 0.18033688011112042f   // 0.125 * log2(e), folded into Q

typedef __attribute__((ext_vector_type(8)))  short  bf16x8;
typedef __attribute__((ext_vector_type(4)))  float  f32x4;

#define MFMA16(a,b,c) __builtin_amdgcn_mfma_f32_16x16x32_bf16(a,b,c,0,0,0)

// ---- device scratch (~97 MB) ----
__device__ float          g_vp[(size_t)M_ * D_];     // roped V projection fp32; later PV partial z=0
__device__ float          g_p1[(size_t)M_ * D_];     // PV partial z=1
__device__ float          g_p2[(size_t)M_ * D_];     // PV partial z=2
__device__ float          g_p3[(size_t)M_ * D_];     // PV partial z=3
__device__ unsigned short g_q16[(size_t)M_ * D_];    // roped+scaled Q  [bh][s][64] (flat view)
__device__ unsigned short g_k16[(size_t)M_ * D_];    // roped K
__device__ unsigned short g_v16t[(size_t)M_ * D_];   // roped,*1/Z, V^T [bh][64 d][2048 s]
__device__ unsigned short g_x16[(size_t)M_ * D_];    // attn out, (b,s,D) layout
__device__ float          g_rz[BH_ * S_];            // 1/Z per (bh, key s)
__device__ float          g_tab[S_ * 64];            // cos/sin interleaved

static __device__ __forceinline__ unsigned short f2b(float x){
  union { float f; unsigned u; } v; v.f = x;
  unsigned r = v.u + 0x7FFFu + ((v.u >> 16) & 1u);   // RNE
  return (unsigned short)(r >> 16);
}
static __device__ __forceinline__ unsigned cvtpk(float lo, float hi){
  unsigned r;
  asm("v_cvt_pk_bf16_f32 %0, %1, %2" : "=v"(r) : "v"(lo), "v"(hi));
  return r;
}

// ------------------------------------------------ cos/sin table
__global__ void k_table(const int* __restrict__ pos){
  int i = blockIdx.x * 256 + threadIdx.x;
  if (i >= S_ * 32) return;
  int s = i >> 5, f = i & 31;
  float ang = (float)pos[s] * powf(10000.0f, -(float)f * (1.0f/32.0f));
  g_tab[2*i]   = cosf(ang);
  g_tab[2*i+1] = sinf(ang);
}

// ------------------------------------------------ Q: RoPE + scale -> bf16 (flat head view)
__global__ void k_ropeq(const float* __restrict__ in){
  const int i = blockIdx.x * 256 + threadIdx.x;   // pair index
  const int grp = i >> 5, d = i & 31;
  const int s = grp & (S_ - 1);                   // s' in (B,H,S,hd) view
  const size_t base = (size_t)grp * 64;
  const float x1 = in[base + d];
  const float x2 = in[base + d + 32];
  const float c  = g_tab[(s*32 + d)*2];
  const float sn = g_tab[(s*32 + d)*2 + 1];
  g_q16[base + d]      = f2b((x1*c - x2*sn) * QKSCALE);
  g_q16[base + d + 32] = f2b((x2*c + x1*sn) * QKSCALE);
}

// ------------------------------------------------ fused K/V projection GEMM (fp32 in, cvt-on-stage)
// z=0: C = rope(key @ Wk^T + bk) -> g_k16 (bf16)
// z=1: C = rope(value @ Wv^T + bv) -> g_vp (fp32)
// RoPE position: projection elem (s, dd) sits at head-view s' = (s&127)*16 + (dd>>6)
__global__ __launch_bounds__(256) void k_proj(const float* __restrict__ key,
                                              const float* __restrict__ value,
                                              const float* __restrict__ Wk,
                                              const float* __restrict__ bk,
                                              const float* __restrict__ Wv,
                                              const float* __restrict__ bv){
  __shared__ __align__(16) unsigned short As[128*64];
  __shared__ __align__(16) unsigned short Bs[128*64];
  const int z = blockIdx.z;
  const float* A    = z ? value : key;
  const float* W    = z ? Wv : Wk;
  const float* bias = z ? bv : bk;
  const int t = threadIdx.x, l = t & 63, wid = t >> 6;
  const int wm = wid >> 1, wn = wid & 1;
  const int rowB = blockIdx.y * 128, colB = blockIdx.x * 128;
  f32x4 acc[4][4];
  #pragma unroll
  for (int i = 0; i < 4; ++i)
    #pragma unroll
    for (int j = 0; j < 4; ++j)
      #pragma unroll
      for (int r = 0; r < 4; ++r) acc[i][j][r] = 0.f;

  const int srow = t >> 3, se = (t & 7) * 8;   // element offset within 64
  float4 a0[4], a1[4], b0[4], b1[4];
#define GLD(K0) \
  for (int u = 0; u < 4; ++u){ \
    const int row = srow + u*32; \
    const float* ap = A + (size_t)(rowB+row)*D_ + (K0) + se; \
    const float* wp = W + (size_t)(colB+row)*D_ + (K0) + se; \
    a0[u] = *(const float4*)ap; a1[u] = *(const float4*)(ap+4); \
    b0[u] = *(const float4*)wp; b1[u] = *(const float4*)(wp+4); \
  }
  GLD(0);
  for (int k0 = 0; k0 < D_; k0 += 64){
    __syncthreads();
    #pragma unroll
    for (int u = 0; u < 4; ++u){
      const int row = srow + u*32;
      const int off = row*128 + ((se*2) ^ ((row & 7) << 4));
      uint4 pa, pb;
      pa.x = cvtpk(a0[u].x, a0[u].y); pa.y = cvtpk(a0[u].z, a0[u].w);
      pa.z = cvtpk(a1[u].x, a1[u].y); pa.w = cvtpk(a1[u].z, a1[u].w);
      pb.x = cvtpk(b0[u].x, b0[u].y); pb.y = cvtpk(b0[u].z, b0[u].w);
      pb.z = cvtpk(b1[u].x, b1[u].y); pb.w = cvtpk(b1[u].z, b1[u].w);
      *(uint4*)((char*)As + off) = pa;
      *(uint4*)((char*)Bs + off) = pb;
    }
    __syncthreads();
    if (k0 + 64 < D_){ GLD(k0 + 64); }
    #pragma unroll
    for (int kk = 0; kk < 2; ++kk){
      const int cb = kk*64 + (l >> 4) * 16;
      bf16x8 af[4], bfr[4];
      #pragma unroll
      for (int mi = 0; mi < 4; ++mi){
        const int row = wm*64 + mi*16 + (l & 15);
        af[mi] = *(const bf16x8*)((const char*)As + row*128 + (cb ^ ((row & 7) << 4)));
      }
      #pragma unroll
      for (int ni = 0; ni < 4; ++ni){
        const int row = wn*64 + ni*16 + (l & 15);
        bfr[ni] = *(const bf16x8*)((const char*)Bs + row*128 + (cb ^ ((row & 7) << 4)));
      }
      #pragma unroll
      for (int mi = 0; mi < 4; ++mi)
        #pragma unroll
        for (int ni = 0; ni < 4; ++ni)
          acc[mi][ni] = MFMA16(af[mi], bfr[ni], acc[mi][ni]);
    }
  }
#undef GLD
  // epilogue: bias + RoPE (pairs are ni and ni+2: cols 32 apart within a head)
  const int ql15 = l & 15, r4 = (l >> 4) * 4;
  const int hcol = (colB >> 6) + wn;              // dd>>6, wave-uniform
  #pragma unroll
  for (int mi = 0; mi < 4; ++mi){
    #pragma unroll
    for (int r = 0; r < 4; ++r){
      const int row = rowB + wm*64 + mi*16 + r4 + r;
      const int pos = ((row & 127) << 4) + hcol;  // head-view position s'
      #pragma unroll
      for (int ni = 0; ni < 2; ++ni){
        const int col = colB + wn*64 + ni*16 + ql15;   // (col & 63) < 32
        const int f = ni*16 + ql15;
        const float c  = g_tab[(pos*32 + f)*2];
        const float sn = g_tab[(pos*32 + f)*2 + 1];
        const float x1 = acc[mi][ni][r]   + bias[col];
        const float x2 = acc[mi][ni+2][r] + bias[col+32];
        const float o1 = x1*c - x2*sn;
        const float o2 = x2*c + x1*sn;
        if (z){
          g_vp[(size_t)row*D_ + col]      = o1;
          g_vp[(size_t)row*D_ + col + 32] = o2;
        } else {
          g_k16[(size_t)row*D_ + col]      = f2b(o1);
          g_k16[(size_t)row*D_ + col + 32] = f2b(o2);
        }
      }
    }
  }
}

// ------------------------------------------------ output GEMM: out = x16 @ Wo^T + bo (Wo fp32, cvt-on-stage)
__global__ __launch_bounds__(256) void k_gemm_out(const unsigned short* __restrict__ A,
                                                  const float* __restrict__ W,
                                                  const float* __restrict__ bias,
                                                  float* __restrict__ C){
  __shared__ __align__(16) unsigned short As[128*64];
  __shared__ __align__(16) unsigned short Bs[128*64];
  const int t = threadIdx.x, l = t & 63, wid = t >> 6;
  const int wm = wid >> 1, wn = wid & 1;
  const int rowB = blockIdx.y * 128, colB = blockIdx.x * 128;
  f32x4 acc[4][4];
  #pragma unroll
  for (int i = 0; i < 4; ++i)
    #pragma unroll
    for (int j = 0; j < 4; ++j)
      #pragma unroll
      for (int r = 0; r < 4; ++r) acc[i][j][r] = 0.f;

  const int srow = t >> 3, se = (t & 7) * 8, scb = (t & 7) * 16;
  float4 ar[4], b0[4], b1[4];
#define GLD(K0) \
  for (int u = 0; u < 4; ++u){ \
    const int row = srow + u*32; \
    ar[u] = *(const float4*)((const char*)(A + (size_t)(rowB+row)*D_ + (K0)) + scb); \
    const float* wp = W + (size_t)(colB+row)*D_ + (K0) + se; \
    b0[u] = *(const float4*)wp; b1[u] = *(const float4*)(wp+4); \
  }
  GLD(0);
  for (int k0 = 0; k0 < D_; k0 += 64){
    __syncthreads();
    #pragma unroll
    for (int u = 0; u < 4; ++u){
      const int row = srow + u*32;
      const int off = row*128 + (scb ^ ((row & 7) << 4));
      uint4 pb;
      pb.x = cvtpk(b0[u].x, b0[u].y); pb.y = cvtpk(b0[u].z, b0[u].w);
      pb.z = cvtpk(b1[u].x, b1[u].y); pb.w = cvtpk(b1[u].z, b1[u].w);
      *(float4*)((char*)As + off) = ar[u];
      *(uint4*)((char*)Bs + off) = pb;
    }
    __syncthreads();
    if (k0 + 64 < D_){ GLD(k0 + 64); }
    #pragma unroll
    for (int kk = 0; kk < 2; ++kk){
      const int cb = kk*64 + (l >> 4) * 16;
      bf16x8 af[4], bfr[4];
      #pragma unroll
      for (int mi = 0; mi < 4; ++mi){
        const int row = wm*64 + mi*16 + (l & 15);
        af[mi] = *(const bf16x8*)((const char*)As + row*128 + (cb ^ ((row & 7) << 4)));
      }
      #pragma unroll
      for (int ni = 0; ni < 4; ++ni){
        const int row = wn*64 + ni*16 + (l & 15);
        bfr[ni] = *(const bf16x8*)((const char*)Bs + row*128 + (cb ^ ((row & 7) << 4)));
      }
      #pragma unroll
      for (int mi = 0; mi < 4; ++mi)
        #pragma unroll
        for (int ni = 0; ni < 4; ++ni)
          acc[mi][ni] = MFMA16(af[mi], bfr[ni], acc[mi][ni]);
    }
  }
#undef GLD
  #pragma unroll
  for (int mi = 0; mi < 4; ++mi){
    #pragma unroll
    for (int ni = 0; ni < 4; ++ni){
      const int col = colB + wn*64 + ni*16 + (l & 15);
      const float bb = bias[col];
      #pragma unroll
      for (int r = 0; r < 4; ++r){
        const int row = rowB + wm*64 + mi*16 + (l >> 4)*4 + r;
        C[(size_t)row * D_ + col] = acc[mi][ni][r] + bb;
      }
    }
  }
}

// ------------------------------------------------ pass 1: Z_k = sum_q exp(s_qk), diag s=0
// block = 4 waves on the SAME 64 keys; each wave sums a 512-q quarter; LDS combine.
__global__ __launch_bounds__(256) void k_pass1(){
  __shared__ float zs[4][4][16];
  const int t = threadIdx.x, l = t & 63, wid = t >> 6;
  const int bh = blockIdx.y;
  const int kwb = blockIdx.x * 64;
  const unsigned short* Qp = g_q16 + (size_t)bh * S_ * HD_;
  const unsigned short* Kp = g_k16 + (size_t)bh * S_ * HD_;
  bf16x8 bk_[4][2];
  #pragma unroll
  for (int kb = 0; kb < 4; ++kb){
    const unsigned short* kr = Kp + (size_t)(kwb + kb*16 + (l & 15)) * HD_ + (l >> 4) * 8;
    bk_[kb][0] = *(const bf16x8*)(kr);
    bk_[kb][1] = *(const bf16x8*)(kr + 32);
  }
  float zz[4] = {0.f, 0.f, 0.f, 0.f};
  const int qBeg = wid * (S_/4);
  for (int qi = 0; qi < S_/4; qi += 16){
    const int q0 = qBeg + qi;
    const unsigned short* qr = Qp + (size_t)(q0 + (l & 15)) * HD_ + (l >> 4) * 8;
    bf16x8 a0 = *(const bf16x8*)(qr);
    bf16x8 a1 = *(const bf16x8*)(qr + 32);
    #pragma unroll
    for (int kb = 0; kb < 4; ++kb){
      f32x4 c = {0.f, 0.f, 0.f, 0.f};
      c = MFMA16(a0, bk_[kb][0], c);
      c = MFMA16(a1, bk_[kb][1], c);
      if (q0 == kwb + kb*16){          // wave-uniform: diagonal tile
        const int kg = kwb + kb*16 + (l & 15);
        #pragma unroll
        for (int r = 0; r < 4; ++r)
          zz[kb] += (q0 + (l >> 4)*4 + r == kg) ? 1.0f : exp2f(c[r]);
      } else {
        zz[kb] += exp2f(c[0]) + exp2f(c[1]) + exp2f(c[2]) + exp2f(c[3]);
      }
    }
  }
  #pragma unroll
  for (int kb = 0; kb < 4; ++kb){
    float z = zz[kb];
    z += __shfl_xor(z, 16); z += __shfl_xor(z, 32);
    if (l < 16) zs[wid][kb][l] = z;
  }
  __syncthreads();
  if (t < 64){
    const int kb = t >> 4, ki = t & 15;
    const float Z = zs[0][kb][ki] + zs[1][kb][ki] + zs[2][kb][ki] + zs[3][kb][ki];
    g_rz[bh*S_ + kwb + kb*16 + ki] = 1.0f / Z;
  }
}

// ------------------------------------------------ V fixup: *1/Z + transpose -> bf16 [bh][d][s] (already roped)
__global__ __launch_bounds__(256) void k_vfix(){
  __shared__ __align__(16) float tile[64][68];
  const int t = threadIdx.x;
  const int bh = blockIdx.y;
  const int s0 = blockIdx.x * 64;
  #pragma unroll
  for (int u = 0; u < 4; ++u){
    const int i = t + u*256;
    const int row = i >> 4, c4 = (i & 15) * 4;
    *(float4*)&tile[row][c4] = *(const float4*)(g_vp + (size_t)(bh*S_ + s0 + row) * HD_ + c4);
  }
  __syncthreads();
  const int d = t >> 2;
  const int sc = (t & 3) * 16;
  float rzv[16];
  #pragma unroll
  for (int u = 0; u < 4; ++u)
    *(float4*)&rzv[u*4] = *(const float4*)(g_rz + bh*S_ + s0 + sc + u*4);
  unsigned w[8];
  #pragma unroll
  for (int j2 = 0; j2 < 8; ++j2)
    w[j2] = cvtpk(tile[sc + 2*j2][d] * rzv[2*j2], tile[sc + 2*j2 + 1][d] * rzv[2*j2 + 1]);
  unsigned short* dst = g_v16t + (size_t)(bh*HD_ + d) * S_ + s0 + sc;
  *(uint4*)(dst)     = *(uint4*)&w[0];
  *(uint4*)(dst + 8) = *(uint4*)&w[4];
}

// ------------------------------------------------ pass 2: out[q,:] = sum_k exp(s_qk) * V'[k,:]
// 4 waves x 32 q; blockIdx.z splits the key range in QUARTERS (fp32 partial outputs).
__global__ __launch_bounds__(256, 4) void k_pass2(){
  __shared__ __align__(16) unsigned short Ks[64*64];     // [k][d]   swizzled
  __shared__ __align__(16) unsigned short Vs[64*64];     // [d][k]   swizzled
  __shared__ __align__(16) unsigned short Ps[4*32*64];   // per-wave [q][k] swizzled
  const int t = threadIdx.x, l = t & 63, wid = t >> 6;
  const int bh = blockIdx.y;
  const int z = blockIdx.z;
  const int b = bh >> 4, hh = bh & 15;
  const int q0 = blockIdx.x * 128;
  const unsigned short* Qp = g_q16  + (size_t)bh * S_ * HD_;
  const unsigned short* Kp = g_k16  + (size_t)bh * S_ * HD_;
  const unsigned short* Vp = g_v16t + (size_t)bh * HD_ * S_;
  float* Op = (z == 0) ? g_vp : (z == 1) ? g_p1 : (z == 2) ? g_p2 : g_p3;
  const int ql = l & 15, kq = l >> 4;
  const int qb = q0 + wid*32;
  char* Pw = (char*)Ps + wid * 4096;

  bf16x8 qf[2][2];
  #pragma unroll
  for (int h = 0; h < 2; ++h){
    const unsigned short* qr = Qp + (size_t)(qb + h*16 + ql) * HD_ + kq * 8;
    qf[h][0] = *(const bf16x8*)(qr);
    qf[h][1] = *(const bf16x8*)(qr + 32);
  }
  f32x4 co[4][2];
  #pragma unroll
  for (int nd = 0; nd < 4; ++nd)
    #pragma unroll
    for (int h = 0; h < 2; ++h)
      #pragma unroll
      for (int r = 0; r < 4; ++r) co[nd][h][r] = 0.f;

  const int srow = t >> 3, scb = (t & 7) * 16;
  const int kg0 = z * (S_/4);
  float4 kreg[2], vreg[2];
  #pragma unroll
  for (int u = 0; u < 2; ++u){
    kreg[u] = *(const float4*)((const char*)(Kp + (size_t)(kg0 + srow + u*32) * HD_) + scb);
    vreg[u] = *(const float4*)((const char*)(Vp + (size_t)(srow + u*32) * S_ + kg0) + scb);
  }
  for (int kt = 0; kt < 8; ++kt){
    const int k0 = kg0 + kt * 64;
    __syncthreads();
    #pragma unroll
    for (int u = 0; u < 2; ++u){
      const int row = srow + u*32;
      const int off = row*128 + (scb ^ ((row & 7) << 4));
      *(float4*)((char*)Ks + off) = kreg[u];
      *(float4*)((char*)Vs + off) = vreg[u];
    }
    __syncthreads();
    if (kt < 7){
      const int k1 = k0 + 64;
      #pragma unroll
      for (int u = 0; u < 2; ++u){
        kreg[u] = *(const float4*)((const char*)(Kp + (size_t)(k1 + srow + u*32) * HD_) + scb);
        vreg[u] = *(const float4*)((const char*)(Vp + (size_t)(srow + u*32) * S_ + k1) + scb);
      }
    }
    // ---- swapped QK^T: D[key16][q16]; A = K rows (shared across q-halves), B = Q
    f32x4 cst[4][2];
    #pragma unroll
    for (int kb = 0; kb < 4; ++kb)
      #pragma unroll
      for (int h = 0; h < 2; ++h)
        #pragma unroll
        for (int r = 0; r < 4; ++r) cst[kb][h][r] = 0.f;
    #pragma unroll
    for (int kb = 0; kb < 4; ++kb){
      const int row = kb*16 + ql;
      #pragma unroll
      for (int s = 0; s < 2; ++s){
        bf16x8 kf = *(const bf16x8*)((const char*)Ks + row*128 + ((s*64 + kq*16) ^ ((row & 7) << 4)));
        cst[kb][0] = MFMA16(kf, qf[0][s], cst[kb][0]);
        cst[kb][1] = MFMA16(kf, qf[1][s], cst[kb][1]);
      }
    }
    // ---- exp -> bf16 pairs -> per-wave LDS (diag handled on overlap tiles only; wave-uniform)
    const bool diag = (k0 < qb + 32) && (qb < k0 + 64);
    #pragma unroll
    for (int h = 0; h < 2; ++h){
      const int qg = qb + h*16 + ql;
      #pragma unroll
      for (int kb = 0; kb < 4; ++kb){
        float e[4];
        if (diag){
          #pragma unroll
          for (int r = 0; r < 4; ++r){
            const int key = k0 + kb*16 + kq*4 + r;
            e[r] = (qg == key) ? 1.0f : exp2f(cst[kb][h][r]);
          }
        } else {
          #pragma unroll
          for (int r = 0; r < 4; ++r) e[r] = exp2f(cst[kb][h][r]);
        }
        uint2 w;
        w.x = cvtpk(e[0], e[1]);
        w.y = cvtpk(e[2], e[3]);
        *(uint2*)(Pw + (h*16 + ql)*128 + ((kb*32 + kq*8) ^ ((ql & 7) << 4))) = w;
      }
    }
    // ---- PV: D[q16][d16]; A = P rows (LDS), B = V' (k x d), shared across q-halves
    #pragma unroll
    for (int sl = 0; sl < 2; ++sl){
      bf16x8 pf0 = *(const bf16x8*)(Pw + (0*16 + ql)*128 + ((sl*64 + kq*16) ^ ((ql & 7) << 4)));
      bf16x8 pf1 = *(const bf16x8*)(Pw + (1*16 + ql)*128 + ((sl*64 + kq*16) ^ ((ql & 7) << 4)));
      #pragma unroll
      for (int nd = 0; nd < 4; ++nd){
        const int row = nd*16 + ql;
        bf16x8 vf = *(const bf16x8*)((const char*)Vs + row*128 + ((sl*64 + kq*16) ^ ((row & 7) << 4)));
        co[nd][0] = MFMA16(pf0, vf, co[nd][0]);
        co[nd][1] = MFMA16(pf1, vf, co[nd][1]);
      }
    }
  }
  // epilogue: fp32 partial, (b,s,D) layout
  #pragma unroll
  for (int h = 0; h < 2; ++h){
    #pragma unroll
    for (int nd = 0; nd < 4; ++nd){
      const int d = nd*16 + ql;
      #pragma unroll
      for (int r = 0; r < 4; ++r){
        const int q = qb + h*16 + kq*4 + r;
        Op[(size_t)(b*S_ + q) * D_ + hh*HD_ + d] = co[nd][h][r];
      }
    }
  }
}

// ------------------------------------------------ combine 4 PV partials -> bf16
__global__ void k_reduce(){
  const int i = blockIdx.x * 256 + threadIdx.x;
  const size_t off = (size_t)i * 8;
  float4 a0 = *(const float4*)(g_vp + off), a1 = *(const float4*)(g_vp + off + 4);
  float4 b0 = *(const float4*)(g_p1 + off), b1 = *(const float4*)(g_p1 + off + 4);
  float4 c0 = *(const float4*)(g_p2 + off), c1 = *(const float4*)(g_p2 + off + 4);
  float4 d0 = *(const float4*)(g_p3 + off), d1 = *(const float4*)(g_p3 + off + 4);
  uint4 w;
  w.x = cvtpk(a0.x + b0.x + c0.x + d0.x, a0.y + b0.y + c0.y + d0.y);
  w.y = cvtpk(a0.z + b0.z + c0.z + d0.z, a0.w + b0.w + c0.w + d0.w);
  w.z = cvtpk(a1.x + b1.x + c1.x + d1.x, a1.y + b1.y + c1.y + d1.y);
  w.w = cvtpk(a1.z + b1.z + c1.z + d1.z, a1.w + b1.w + c1.w + d1.w);
  *(uint4*)(g_x16 + off) = w;
}

extern "C" void kernel_launch(void* const* d_in, const int* in_sizes, int n_in,
                              void* d_out, int out_size, void* d_ws, size_t ws_size,
                              hipStream_t stream) {
  const float* query = (const float*)d_in[0];
  const float* key   = (const float*)d_in[1];
  const float* value = (const float*)d_in[2];
  const int*   pos   = (const int*)  d_in[3];
  const float* Wk    = (const float*)d_in[4];
  const float* bk    = (const float*)d_in[5];
  const float* Wv    = (const float*)d_in[6];
  const float* bv    = (const float*)d_in[7];
  const float* Wo    = (const float*)d_in[8];
  const float* bo    = (const float*)d_in[9];
  float* out = (float*)d_out;

  unsigned short* px16; hipGetSymbolAddress((void**)&px16, HIP_SYMBOL(g_x16));

  k_table<<<256, 256, 0, stream>>>(pos);

  dim3 gP(D_/128, M_/128, 2);   // (8, 32, 2)
  k_proj<<<gP, 256, 0, stream>>>(key, value, Wk, bk, Wv, bv);  // -> g_k16 (roped bf16), g_vp (roped fp32)

  k_ropeq<<<8192, 256, 0, stream>>>(query);                    // -> g_q16 (roped, scaled)

  k_pass1<<<dim3(S_/64, BH_), 256, 0, stream>>>();             // -> g_rz   (1024 blocks)
  k_vfix <<<dim3(32, BH_), 256, 0, stream>>>();                // g_vp -> g_v16t (*1/Z, transposed)
  k_pass2<<<dim3(16, BH_, 4), 256, 0, stream>>>();             // -> 4 fp32 partials (2048 blocks)
  k_reduce<<<(M_*D_/8)/256, 256, 0, stream>>>();               // -> g_x16

  dim3 gO(D_/128, M_/128);      // (8, 32)
  k_gemm_out<<<gO, 256, 0, stream>>>(px16, Wo, bo, out);       // output proj
}